// Round 1
// baseline (216.652 us; speedup 1.0000x reference)
//
#include <hip/hip_runtime.h>
#include <math.h>

typedef __attribute__((ext_vector_type(8))) short bf16x8;
typedef __attribute__((ext_vector_type(4))) float f32x4;

constexpr int kN   = 50000;
constexpr int kR   = 8;
constexpr int kIn  = 128;
constexpr int kHid = 128;
constexpr int kOut = 40;
constexpr int kNT  = 16;              // dst nodes per block
constexpr int kLds = 1032;            // ushort row stride (16B-aligned rows)
constexpr float kBnEps = 1e-5f;

// bf16 helpers
__device__ inline float bf2f(ushort s) { return __uint_as_float(((uint)s) << 16); }

// v_cvt_pk_bf16_f32: lo = bf16(a), hi = bf16(b), RNE. No builtin on gfx950.
__device__ __forceinline__ uint cvtpk(float a, float b) {
    uint r;
    asm("v_cvt_pk_bf16_f32 %0, %1, %2" : "=v"(r) : "v"(a), "v"(b));
    return r;
}

// ---------------------------------------------------------------------------
// prep: fused  (a) cast x fp32->bf16   [blocks 0..3124, 256 thr x 8 elems]
//              (b) pack W1 into MFMA B-fragment order [blocks 3125..3188]
//              (c) pack W2                            [blocks 3189..3212]
// Fragment f = nt*32 + kt; lane L holds B[n = nt*16 + (L&15)][k = kt*32 + (L>>4)*8 + j].
// ---------------------------------------------------------------------------
__device__ __forceinline__ void pack_unit(const float* __restrict__ W,
                                          ushort* __restrict__ dst,
                                          int N, int frag, int lane)
{
    const int kt = frag & 31;
    const int nt = frag >> 5;
    const int n  = nt * 16 + (lane & 15);
    const int q  = lane >> 4;
    float f[8];
    #pragma unroll
    for (int j = 0; j < 8; ++j) {
        const int k = kt * 32 + q * 8 + j;
        f[j] = (n < N) ? W[(size_t)k * N + n] : 0.f;
    }
    const size_t o = ((size_t)frag * 64 + lane) * 8;
    *(uint4*)&dst[o] = make_uint4(cvtpk(f[0], f[1]), cvtpk(f[2], f[3]),
                                  cvtpk(f[4], f[5]), cvtpk(f[6], f[7]));
}

__global__ __launch_bounds__(256)
void prep(const float* __restrict__ x,  ushort* __restrict__ xb,
          const float* __restrict__ W1, ushort* __restrict__ W1hi,
          const float* __restrict__ W2, ushort* __restrict__ W2hi)
{
    const int b   = blockIdx.x;
    const int tid = threadIdx.x;
    if (b < 3125) {
        const size_t i = ((size_t)b * 256 + tid) * 8;
        const float4 v0 = *(const float4*)&x[i];
        const float4 v1 = *(const float4*)&x[i + 4];
        *(uint4*)&xb[i] = make_uint4(cvtpk(v0.x, v0.y), cvtpk(v0.z, v0.w),
                                     cvtpk(v1.x, v1.y), cvtpk(v1.z, v1.w));
    } else if (b < 3125 + 64) {
        pack_unit(W1, W1hi, kHid, (b - 3125) * 4 + (tid >> 6), tid & 63);
    } else {
        const int frag = (b - 3189) * 4 + (tid >> 6);
        if (frag < 96) pack_unit(W2, W2hi, kOut, frag, tid & 63);
    }
}

// ---------------------------------------------------------------------------
// Phase A: 8 waves x 2 nodes; lane owns bf16 pair d = lane*2, lane*2+1.
// All 32 gathers (both nodes) issued back-to-back, pinned live via asm
// keep-alive fence (defeats compiler VGPR-chunking -> one latency exposure),
// then balanced-tree wave-uniform accumulate, cvt_pk_bf16 stores.
// ---------------------------------------------------------------------------
#define ACCUM_ET(ET, VX, VY)                                                   \
    if ((ET) < 4) {                                                            \
        if ((ET) < 2) {                                                        \
            if ((ET) == 0) { a0.x += (VX); a0.y += (VY); }                     \
            else           { a1.x += (VX); a1.y += (VY); }                     \
        } else {                                                               \
            if ((ET) == 2) { a2.x += (VX); a2.y += (VY); }                     \
            else           { a3.x += (VX); a3.y += (VY); }                     \
        }                                                                      \
    } else {                                                                   \
        if ((ET) < 6) {                                                        \
            if ((ET) == 4) { a4.x += (VX); a4.y += (VY); }                     \
            else           { a5.x += (VX); a5.y += (VY); }                     \
        } else {                                                               \
            if ((ET) == 6) { a6.x += (VX); a6.y += (VY); }                     \
            else           { a7.x += (VX); a7.y += (VY); }                     \
        }                                                                      \
    }

#define RD(V, J) __builtin_amdgcn_readlane((V), (J))

#define G(BV, VI, J)                                                           \
    const ushort2 BV = *(const ushort2*)&feat[(size_t)RD(VI, J) * 128 + d2];

#define ACCUM_EDGE(VE, J, BV)                                                  \
    { const int et = RD(VE, J);                                                \
      const float vx = bf2f(BV.x), vy = bf2f(BV.y);                            \
      ACCUM_ET(et, vx, vy) }

#define ZERO_ACC                                                               \
    float2 a0 = {0.f,0.f}, a1 = {0.f,0.f}, a2 = {0.f,0.f}, a3 = {0.f,0.f};     \
    float2 a4 = {0.f,0.f}, a5 = {0.f,0.f}, a6 = {0.f,0.f}, a7 = {0.f,0.f};

#define STORE8(NN)                                                             \
    { const int nloc = (NN);                                                   \
      *(uint*)&aggHi[nloc][0 * 128 + d2] = cvtpk(a0.x, a0.y);                  \
      *(uint*)&aggHi[nloc][1 * 128 + d2] = cvtpk(a1.x, a1.y);                  \
      *(uint*)&aggHi[nloc][2 * 128 + d2] = cvtpk(a2.x, a2.y);                  \
      *(uint*)&aggHi[nloc][3 * 128 + d2] = cvtpk(a3.x, a3.y);                  \
      *(uint*)&aggHi[nloc][4 * 128 + d2] = cvtpk(a4.x, a4.y);                  \
      *(uint*)&aggHi[nloc][5 * 128 + d2] = cvtpk(a5.x, a5.y);                  \
      *(uint*)&aggHi[nloc][6 * 128 + d2] = cvtpk(a6.x, a6.y);                  \
      *(uint*)&aggHi[nloc][7 * 128 + d2] = cvtpk(a7.x, a7.y); }

#define KEEP16(B0,B1,B2,B3,B4,B5,B6,B7,B8,B9,B10,B11,B12,B13,B14,B15)          \
    asm volatile("" :: "v"(B0),"v"(B1),"v"(B2),"v"(B3),                        \
                       "v"(B4),"v"(B5),"v"(B6),"v"(B7),                        \
                       "v"(B8),"v"(B9),"v"(B10),"v"(B11),                      \
                       "v"(B12),"v"(B13),"v"(B14),"v"(B15));

__device__ __forceinline__ void phaseA_bf16(const ushort* __restrict__ feat,
                                            const int* __restrict__ ptr,
                                            const int* __restrict__ idx,
                                            const int* __restrict__ etype,
                                            int base, ushort (*aggHi)[kLds])
{
    const int lane = threadIdx.x & 63;
    const int wid  = threadIdx.x >> 6;            // 8 waves
    const int d2   = lane * 2;

    const int node0 = base + wid * 2;
    const int p0 = ptr[node0];
    const int p1 = ptr[node0 + 1];
    const int p2 = ptr[node0 + 2];

    if (((p1 - p0) == 16) & ((p2 - p1) == 16)) {  // fixed-degree fast path
        const int vi0 = idx[p0 + (lane & 15)];
        const int ve0 = etype[p0 + (lane & 15)];
        const int vi1 = idx[p1 + (lane & 15)];
        const int ve1 = etype[p1 + (lane & 15)];

        // node 0 gathers
        G(b0,  vi0, 0)  G(b1,  vi0, 1)  G(b2,  vi0, 2)  G(b3,  vi0, 3)
        G(b4,  vi0, 4)  G(b5,  vi0, 5)  G(b6,  vi0, 6)  G(b7,  vi0, 7)
        G(b8,  vi0, 8)  G(b9,  vi0, 9)  G(b10, vi0, 10) G(b11, vi0, 11)
        G(b12, vi0, 12) G(b13, vi0, 13) G(b14, vi0, 14) G(b15, vi0, 15)
        // node 1 gathers
        G(c0,  vi1, 0)  G(c1,  vi1, 1)  G(c2,  vi1, 2)  G(c3,  vi1, 3)
        G(c4,  vi1, 4)  G(c5,  vi1, 5)  G(c6,  vi1, 6)  G(c7,  vi1, 7)
        G(c8,  vi1, 8)  G(c9,  vi1, 9)  G(c10, vi1, 10) G(c11, vi1, 11)
        G(c12, vi1, 12) G(c13, vi1, 13) G(c14, vi1, 14) G(c15, vi1, 15)

        // Pin all 32 results live: forces full-depth MLP (one latency
        // exposure) instead of compiler-chunked 4-at-a-time gathers.
        KEEP16(b0,b1,b2,b3,b4,b5,b6,b7,b8,b9,b10,b11,b12,b13,b14,b15)
        KEEP16(c0,c1,c2,c3,c4,c5,c6,c7,c8,c9,c10,c11,c12,c13,c14,c15)

        {
            ZERO_ACC
            ACCUM_EDGE(ve0, 0,  b0)  ACCUM_EDGE(ve0, 1,  b1)
            ACCUM_EDGE(ve0, 2,  b2)  ACCUM_EDGE(ve0, 3,  b3)
            ACCUM_EDGE(ve0, 4,  b4)  ACCUM_EDGE(ve0, 5,  b5)
            ACCUM_EDGE(ve0, 6,  b6)  ACCUM_EDGE(ve0, 7,  b7)
            ACCUM_EDGE(ve0, 8,  b8)  ACCUM_EDGE(ve0, 9,  b9)
            ACCUM_EDGE(ve0, 10, b10) ACCUM_EDGE(ve0, 11, b11)
            ACCUM_EDGE(ve0, 12, b12) ACCUM_EDGE(ve0, 13, b13)
            ACCUM_EDGE(ve0, 14, b14) ACCUM_EDGE(ve0, 15, b15)
            STORE8(wid * 2)
        }
        {
            ZERO_ACC
            ACCUM_EDGE(ve1, 0,  c0)  ACCUM_EDGE(ve1, 1,  c1)
            ACCUM_EDGE(ve1, 2,  c2)  ACCUM_EDGE(ve1, 3,  c3)
            ACCUM_EDGE(ve1, 4,  c4)  ACCUM_EDGE(ve1, 5,  c5)
            ACCUM_EDGE(ve1, 6,  c6)  ACCUM_EDGE(ve1, 7,  c7)
            ACCUM_EDGE(ve1, 8,  c8)  ACCUM_EDGE(ve1, 9,  c9)
            ACCUM_EDGE(ve1, 10, c10) ACCUM_EDGE(ve1, 11, c11)
            ACCUM_EDGE(ve1, 12, c12) ACCUM_EDGE(ve1, 13, c13)
            ACCUM_EDGE(ve1, 14, c14) ACCUM_EDGE(ve1, 15, c15)
            STORE8(wid * 2 + 1)
        }
    } else {                                      // generic fallback (never hit)
        #pragma unroll
        for (int t = 0; t < 2; ++t) {
            const int node = node0 + t;
            const int pa   = ptr[node];
            const int deg  = ptr[node + 1] - pa;
            ZERO_ACC
            for (int e = pa; e < pa + deg; ++e) {
                const int src = __builtin_amdgcn_readfirstlane(idx[e]);
                const int et  = __builtin_amdgcn_readfirstlane(etype[e]);
                const ushort2 u = *(const ushort2*)&feat[(size_t)src * 128 + d2];
                const float vx = bf2f(u.x), vy = bf2f(u.y);
                ACCUM_ET(et, vx, vy)
            }
            STORE8(wid * 2 + t)
        }
    }
}

// ---------------------------------------------------------------------------
// Layer 1: h1 = bf16( relu(bn( (sum_r agg_r @ W1[r]) / deg )) )
// ---------------------------------------------------------------------------
__global__ __launch_bounds__(512, 4)
void rgcn_layer1(const ushort* __restrict__ xb,
                 const ushort* __restrict__ W1hi,
                 const float* __restrict__ gamma, const float* __restrict__ beta,
                 const float* __restrict__ mean,  const float* __restrict__ var,
                 const int* __restrict__ ptr, const int* __restrict__ idx,
                 const int* __restrict__ etype,
                 ushort* __restrict__ h1b)
{
    __shared__ ushort aggHi[kNT][kLds];           // 33 KB
    const int tid  = threadIdx.x;
    const int base = blockIdx.x * kNT;

    phaseA_bf16(xb, ptr, idx, etype, base, aggHi);
    __syncthreads();

    const int lane = tid & 63;
    const int wid  = tid >> 6;                    // n-tile owned by this wave
    const int m    = lane & 15;
    const int q    = lane >> 4;

    const bf16x8* Bh = (const bf16x8*)W1hi + (size_t)wid * 32 * 64 + lane;
    f32x4 acc = {0.f, 0.f, 0.f, 0.f};

    #pragma unroll 4
    for (int kt = 0; kt < 32; ++kt) {
        const bf16x8 ah = *(const bf16x8*)&aggHi[m][kt * 32 + q * 8];
        const bf16x8 bh = Bh[(size_t)kt * 64];
        acc = __builtin_amdgcn_mfma_f32_16x16x32_bf16(ah, bh, acc, 0, 0, 0);
    }

    // Epilogue: deg norm + BN + ReLU, write bf16 h1 (packed conversions)
    const int c = wid * 16 + m;
    const float g  = gamma[c] * rsqrtf(var[c] + kBnEps);
    const float mu = mean[c];
    const float bt = beta[c];
    float v[4];
    #pragma unroll
    for (int i = 0; i < 4; ++i) {
        const int node = base + q * 4 + i;
        const float invdeg = 1.0f / (float)(ptr[node + 1] - ptr[node]);
        v[i] = fmaxf((acc[i] * invdeg - mu) * g + bt, 0.f);
    }
    const uint p01 = cvtpk(v[0], v[1]);
    const uint p23 = cvtpk(v[2], v[3]);
    const int n0 = base + q * 4;
    h1b[(size_t)(n0 + 0) * kHid + c] = (ushort)(p01 & 0xFFFFu);
    h1b[(size_t)(n0 + 1) * kHid + c] = (ushort)(p01 >> 16);
    h1b[(size_t)(n0 + 2) * kHid + c] = (ushort)(p23 & 0xFFFFu);
    h1b[(size_t)(n0 + 3) * kHid + c] = (ushort)(p23 >> 16);
}

// ---------------------------------------------------------------------------
// Layer 2: out = log_softmax( (sum_r agg_r @ W2[r]) / deg ), N padded 40->48
// ---------------------------------------------------------------------------
__global__ __launch_bounds__(512, 4)
void rgcn_layer2(const ushort* __restrict__ h1b,
                 const ushort* __restrict__ W2hi,
                 const int* __restrict__ ptr, const int* __restrict__ idx,
                 const int* __restrict__ etype,
                 float* __restrict__ out)
{
    __shared__ ushort aggHi[kNT][kLds];           // 33 KB
    __shared__ float logits[kNT][48];             // 3 KB
    const int tid  = threadIdx.x;
    const int base = blockIdx.x * kNT;

    phaseA_bf16(h1b, ptr, idx, etype, base, aggHi);
    __syncthreads();

    const int lane = tid & 63;
    const int wid  = tid >> 6;
    const int m    = lane & 15;
    const int q    = lane >> 4;

    if (wid < 3) {                                // n-tiles 0..2 cover 48 cols
        const bf16x8* Bh = (const bf16x8*)W2hi + (size_t)wid * 32 * 64 + lane;
        f32x4 acc = {0.f, 0.f, 0.f, 0.f};
        #pragma unroll 4
        for (int kt = 0; kt < 32; ++kt) {
            const bf16x8 ah = *(const bf16x8*)&aggHi[m][kt * 32 + q * 8];
            const bf16x8 bh = Bh[(size_t)kt * 64];
            acc = __builtin_amdgcn_mfma_f32_16x16x32_bf16(ah, bh, acc, 0, 0, 0);
        }
        const int n = wid * 16 + m;               // logit column
        if (n < kOut) {
            #pragma unroll
            for (int i = 0; i < 4; ++i) {
                const int node = base + q * 4 + i;
                const float invdeg = 1.0f / (float)(ptr[node + 1] - ptr[node]);
                logits[q * 4 + i][n] = acc[i] * invdeg;
            }
        }
    }
    __syncthreads();

    // log_softmax: wave w handles nodes w*2, w*2+1
    #pragma unroll
    for (int i = 0; i < 2; ++i) {
        const int nrow = wid * 2 + i;
        const int node = base + nrow;
        const float v = (lane < kOut) ? logits[nrow][lane] : -INFINITY;
        float mx = v;
        #pragma unroll
        for (int off = 32; off > 0; off >>= 1)
            mx = fmaxf(mx, __shfl_xor(mx, off, 64));
        float s = (lane < kOut) ? __expf(v - mx) : 0.f;
        #pragma unroll
        for (int off = 32; off > 0; off >>= 1)
            s += __shfl_xor(s, off, 64);
        if (lane < kOut)
            out[(size_t)node * kOut + lane] = v - mx - __logf(s);
    }
}

// ---------------------------------------------------------------------------
extern "C" void kernel_launch(void* const* d_in, const int* in_sizes, int n_in,
                              void* d_out, int out_size, void* d_ws, size_t ws_size,
                              hipStream_t stream)
{
    const float* x     = (const float*)d_in[0];
    const float* W1    = (const float*)d_in[1];
    const float* W2    = (const float*)d_in[2];
    const float* gamma = (const float*)d_in[3];
    const float* beta  = (const float*)d_in[4];
    const float* mean  = (const float*)d_in[5];
    const float* var   = (const float*)d_in[6];
    const int*   ptr   = (const int*)d_in[7];
    const int*   idx   = (const int*)d_in[8];
    const int*   et    = (const int*)d_in[9];
    float*       out   = (float*)d_out;

    // Workspace (~26 MB)
    char* ws = (char*)d_ws;
    ushort* h1b  = (ushort*)ws;                              // 12,800,000 B
    ushort* xb   = (ushort*)(ws + 12800000);                 // 12,800,000 B
    ushort* W1hi = (ushort*)(ws + 25600000);                 //    262,144 B
    ushort* W2hi = (ushort*)(ws + 25600000 + 262144);        //     98,304 B

    prep<<<dim3(3125 + 64 + 24), dim3(256), 0, stream>>>(x, xb, W1, W1hi, W2, W2hi);

    dim3 grid(kN / kNT), block(512);
    rgcn_layer1<<<grid, block, 0, stream>>>(xb, W1hi, gamma, beta, mean, var,
                                            ptr, idx, et, h1b);
    rgcn_layer2<<<grid, block, 0, stream>>>(h1b, W2hi, ptr, idx, et, out);
}

// Round 2
// 199.656 us; speedup vs baseline: 1.0851x; 1.0851x over previous
//
#include <hip/hip_runtime.h>
#include <math.h>

typedef __attribute__((ext_vector_type(8))) short bf16x8;
typedef __attribute__((ext_vector_type(4))) float f32x4;

constexpr int kN   = 50000;
constexpr int kR   = 8;
constexpr int kIn  = 128;
constexpr int kHid = 128;
constexpr int kOut = 40;
constexpr int kNT  = 32;              // dst nodes per block (16 waves x 2)
constexpr int kLds = 1032;            // ushort row stride (16B-aligned rows)
constexpr float kBnEps = 1e-5f;

// bf16 helpers
__device__ inline float bf2f(ushort s) { return __uint_as_float(((uint)s) << 16); }

// v_cvt_pk_bf16_f32: lo = bf16(a), hi = bf16(b), RNE. No builtin on gfx950.
__device__ __forceinline__ uint cvtpk(float a, float b) {
    uint r;
    asm("v_cvt_pk_bf16_f32 %0, %1, %2" : "=v"(r) : "v"(a), "v"(b));
    return r;
}

// ---------------------------------------------------------------------------
// prep: fused  (a) cast x fp32->bf16   [blocks 0..3124, 256 thr x 8 elems]
//              (b) pack W1 into MFMA B-fragment order [blocks 3125..3188]
//              (c) pack W2                            [blocks 3189..3212]
// Fragment f = nt*32 + kt; lane L holds B[n = nt*16 + (L&15)][k = kt*32 + (L>>4)*8 + j].
// ---------------------------------------------------------------------------
__device__ __forceinline__ void pack_unit(const float* __restrict__ W,
                                          ushort* __restrict__ dst,
                                          int N, int frag, int lane)
{
    const int kt = frag & 31;
    const int nt = frag >> 5;
    const int n  = nt * 16 + (lane & 15);
    const int q  = lane >> 4;
    float f[8];
    #pragma unroll
    for (int j = 0; j < 8; ++j) {
        const int k = kt * 32 + q * 8 + j;
        f[j] = (n < N) ? W[(size_t)k * N + n] : 0.f;
    }
    const size_t o = ((size_t)frag * 64 + lane) * 8;
    *(uint4*)&dst[o] = make_uint4(cvtpk(f[0], f[1]), cvtpk(f[2], f[3]),
                                  cvtpk(f[4], f[5]), cvtpk(f[6], f[7]));
}

__global__ __launch_bounds__(256)
void prep(const float* __restrict__ x,  ushort* __restrict__ xb,
          const float* __restrict__ W1, ushort* __restrict__ W1hi,
          const float* __restrict__ W2, ushort* __restrict__ W2hi)
{
    const int b   = blockIdx.x;
    const int tid = threadIdx.x;
    if (b < 3125) {
        const size_t i = ((size_t)b * 256 + tid) * 8;
        const float4 v0 = *(const float4*)&x[i];
        const float4 v1 = *(const float4*)&x[i + 4];
        *(uint4*)&xb[i] = make_uint4(cvtpk(v0.x, v0.y), cvtpk(v0.z, v0.w),
                                     cvtpk(v1.x, v1.y), cvtpk(v1.z, v1.w));
    } else if (b < 3125 + 64) {
        pack_unit(W1, W1hi, kHid, (b - 3125) * 4 + (tid >> 6), tid & 63);
    } else {
        const int frag = (b - 3189) * 4 + (tid >> 6);
        if (frag < 96) pack_unit(W2, W2hi, kOut, frag, tid & 63);
    }
}

// ---------------------------------------------------------------------------
// Phase A (R6-proven structure): NO private arrays (named scalars only).
// 16 waves x 2 sequential nodes; lane owns bf16 pair d = lane*2, lane*2+1.
// Per node: 16 gathers issued back-to-back (compiler chunk-pipelines them),
// then wave-uniform branch-tree accumulate. NO asm fences (R1 lesson: the
// forced vmcnt(0) killed the compiler's load/compute overlap).
// Only deltas vs R6: idx/etype for node 1 hoisted before node 0's gathers
// (overlaps t=1 index fetch with t=0 compute), cvt_pk_bf16 stores.
// ---------------------------------------------------------------------------
#define ACCUM_ET(ET, VX, VY)                                                   \
    if ((ET) < 4) {                                                            \
        if ((ET) < 2) {                                                        \
            if ((ET) == 0) { a0.x += (VX); a0.y += (VY); }                     \
            else           { a1.x += (VX); a1.y += (VY); }                     \
        } else {                                                               \
            if ((ET) == 2) { a2.x += (VX); a2.y += (VY); }                     \
            else           { a3.x += (VX); a3.y += (VY); }                     \
        }                                                                      \
    } else {                                                                   \
        if ((ET) < 6) {                                                        \
            if ((ET) == 4) { a4.x += (VX); a4.y += (VY); }                     \
            else           { a5.x += (VX); a5.y += (VY); }                     \
        } else {                                                               \
            if ((ET) == 6) { a6.x += (VX); a6.y += (VY); }                     \
            else           { a7.x += (VX); a7.y += (VY); }                     \
        }                                                                      \
    }

#define RD(V, J) __builtin_amdgcn_readlane((V), (J))

#define GATHER(BV, SRC) \
    const ushort2 BV = *(const ushort2*)&feat[(size_t)(SRC) * 128 + d2];

#define ACCUM_EDGE(VE, J, BV)                                                  \
    { const int et = RD(VE, J);                                                \
      const float vx = bf2f(BV.x), vy = bf2f(BV.y);                            \
      ACCUM_ET(et, vx, vy) }

#define ZERO_ACC                                                               \
    float2 a0 = {0.f,0.f}, a1 = {0.f,0.f}, a2 = {0.f,0.f}, a3 = {0.f,0.f};     \
    float2 a4 = {0.f,0.f}, a5 = {0.f,0.f}, a6 = {0.f,0.f}, a7 = {0.f,0.f};

#define STORE8(NN)                                                             \
    { const int nloc = (NN);                                                   \
      *(uint*)&aggHi[nloc][0 * 128 + d2] = cvtpk(a0.x, a0.y);                  \
      *(uint*)&aggHi[nloc][1 * 128 + d2] = cvtpk(a1.x, a1.y);                  \
      *(uint*)&aggHi[nloc][2 * 128 + d2] = cvtpk(a2.x, a2.y);                  \
      *(uint*)&aggHi[nloc][3 * 128 + d2] = cvtpk(a3.x, a3.y);                  \
      *(uint*)&aggHi[nloc][4 * 128 + d2] = cvtpk(a4.x, a4.y);                  \
      *(uint*)&aggHi[nloc][5 * 128 + d2] = cvtpk(a5.x, a5.y);                  \
      *(uint*)&aggHi[nloc][6 * 128 + d2] = cvtpk(a6.x, a6.y);                  \
      *(uint*)&aggHi[nloc][7 * 128 + d2] = cvtpk(a7.x, a7.y); }

#define NODE_BODY(VI, VE, NLOC)                                                \
    {                                                                          \
        const int s0  = RD(VI, 0);  const int s1  = RD(VI, 1);                 \
        const int s2  = RD(VI, 2);  const int s3  = RD(VI, 3);                 \
        const int s4  = RD(VI, 4);  const int s5  = RD(VI, 5);                 \
        const int s6  = RD(VI, 6);  const int s7  = RD(VI, 7);                 \
        const int s8  = RD(VI, 8);  const int s9  = RD(VI, 9);                 \
        const int s10 = RD(VI, 10); const int s11 = RD(VI, 11);                \
        const int s12 = RD(VI, 12); const int s13 = RD(VI, 13);                \
        const int s14 = RD(VI, 14); const int s15 = RD(VI, 15);                \
        GATHER(b0,  s0)  GATHER(b1,  s1)  GATHER(b2,  s2)  GATHER(b3,  s3)     \
        GATHER(b4,  s4)  GATHER(b5,  s5)  GATHER(b6,  s6)  GATHER(b7,  s7)     \
        GATHER(b8,  s8)  GATHER(b9,  s9)  GATHER(b10, s10) GATHER(b11, s11)    \
        GATHER(b12, s12) GATHER(b13, s13) GATHER(b14, s14) GATHER(b15, s15)    \
        ZERO_ACC                                                               \
        ACCUM_EDGE(VE, 0,  b0)  ACCUM_EDGE(VE, 1,  b1)                         \
        ACCUM_EDGE(VE, 2,  b2)  ACCUM_EDGE(VE, 3,  b3)                         \
        ACCUM_EDGE(VE, 4,  b4)  ACCUM_EDGE(VE, 5,  b5)                         \
        ACCUM_EDGE(VE, 6,  b6)  ACCUM_EDGE(VE, 7,  b7)                         \
        ACCUM_EDGE(VE, 8,  b8)  ACCUM_EDGE(VE, 9,  b9)                         \
        ACCUM_EDGE(VE, 10, b10) ACCUM_EDGE(VE, 11, b11)                        \
        ACCUM_EDGE(VE, 12, b12) ACCUM_EDGE(VE, 13, b13)                        \
        ACCUM_EDGE(VE, 14, b14) ACCUM_EDGE(VE, 15, b15)                        \
        STORE8(NLOC)                                                           \
    }

__device__ __forceinline__ void phaseA_bf16(const ushort* __restrict__ feat,
                                            const int* __restrict__ ptr,
                                            const int* __restrict__ idx,
                                            const int* __restrict__ etype,
                                            int base, ushort (*aggHi)[kLds])
{
    const int lane = threadIdx.x & 63;
    const int wid  = threadIdx.x >> 6;            // 16 waves
    const int d2   = lane * 2;

    const int node0 = base + wid * 2;
    if (node0 >= kN) return;                      // tail block: rows unused
    const int p0 = ptr[node0];
    const int p1 = ptr[node0 + 1];
    const int p2 = ptr[node0 + 2];

    if (((p1 - p0) == 16) & ((p2 - p1) == 16)) {  // fixed-degree fast path
        const int vi0 = idx[p0 + (lane & 15)];
        const int ve0 = etype[p0 + (lane & 15)];
        const int vi1 = idx[p1 + (lane & 15)];    // hoisted: overlaps node-0 compute
        const int ve1 = etype[p1 + (lane & 15)];
        NODE_BODY(vi0, ve0, wid * 2)
        NODE_BODY(vi1, ve1, wid * 2 + 1)
    } else {                                      // generic fallback (never hit)
        #pragma unroll
        for (int t = 0; t < 2; ++t) {
            const int node = node0 + t;
            const int pa   = ptr[node];
            const int deg  = ptr[node + 1] - pa;
            ZERO_ACC
            for (int e = pa; e < pa + deg; ++e) {
                const int src = __builtin_amdgcn_readfirstlane(idx[e]);
                const int et  = __builtin_amdgcn_readfirstlane(etype[e]);
                const ushort2 u = *(const ushort2*)&feat[(size_t)src * 128 + d2];
                const float vx = bf2f(u.x), vy = bf2f(u.y);
                ACCUM_ET(et, vx, vy)
            }
            STORE8(wid * 2 + t)
        }
    }
}

// ---------------------------------------------------------------------------
// Layer 1: h1 = bf16( relu(bn( (sum_r agg_r @ W1[r]) / deg )) )
// kNT=32 / 1024 threads: halves per-block W1 re-reads from L2 (was the
// phase-B bottleneck: 3125 x 256KB = 800MB of L2 traffic; now 400MB).
// 16 waves -> 2x8 grid of 16x16 output tiles (mi = wid>>3, ni = wid&7).
// ---------------------------------------------------------------------------
__global__ __launch_bounds__(1024, 4)
void rgcn_layer1(const ushort* __restrict__ xb,
                 const ushort* __restrict__ W1hi,
                 const float* __restrict__ gamma, const float* __restrict__ beta,
                 const float* __restrict__ mean,  const float* __restrict__ var,
                 const int* __restrict__ ptr, const int* __restrict__ idx,
                 const int* __restrict__ etype,
                 ushort* __restrict__ h1b)
{
    __shared__ ushort aggHi[kNT][kLds];           // 66 KB -> 2 blocks/CU
    const int tid  = threadIdx.x;
    const int base = blockIdx.x * kNT;

    phaseA_bf16(xb, ptr, idx, etype, base, aggHi);
    __syncthreads();

    const int lane = tid & 63;
    const int wid  = tid >> 6;
    const int m    = lane & 15;
    const int q    = lane >> 4;
    const int ni   = wid & 7;                     // output col tile (16 cols)
    const int mi   = wid >> 3;                    // output row half (16 rows)

    const bf16x8* Bh = (const bf16x8*)W1hi + (size_t)ni * 32 * 64 + lane;
    f32x4 acc = {0.f, 0.f, 0.f, 0.f};

    #pragma unroll 4
    for (int kt = 0; kt < 32; ++kt) {
        const bf16x8 ah = *(const bf16x8*)&aggHi[mi * 16 + m][kt * 32 + q * 8];
        const bf16x8 bh = Bh[(size_t)kt * 64];
        acc = __builtin_amdgcn_mfma_f32_16x16x32_bf16(ah, bh, acc, 0, 0, 0);
    }

    // Epilogue: deg norm + BN + ReLU, write bf16 h1 (packed conversions)
    const int c = ni * 16 + m;
    const float g  = gamma[c] * rsqrtf(var[c] + kBnEps);
    const float mu = mean[c];
    const float bt = beta[c];
    const int n0 = base + mi * 16 + q * 4;
    float v[4];
    #pragma unroll
    for (int i = 0; i < 4; ++i) {
        const int node = n0 + i;
        float invdeg = 1.0f;
        if (node < kN) invdeg = 1.0f / (float)(ptr[node + 1] - ptr[node]);
        v[i] = fmaxf((acc[i] * invdeg - mu) * g + bt, 0.f);
    }
    const uint p01 = cvtpk(v[0], v[1]);
    const uint p23 = cvtpk(v[2], v[3]);
    if (n0 + 0 < kN) h1b[(size_t)(n0 + 0) * kHid + c] = (ushort)(p01 & 0xFFFFu);
    if (n0 + 1 < kN) h1b[(size_t)(n0 + 1) * kHid + c] = (ushort)(p01 >> 16);
    if (n0 + 2 < kN) h1b[(size_t)(n0 + 2) * kHid + c] = (ushort)(p23 & 0xFFFFu);
    if (n0 + 3 < kN) h1b[(size_t)(n0 + 3) * kHid + c] = (ushort)(p23 >> 16);
}

// ---------------------------------------------------------------------------
// Layer 2: out = log_softmax( (sum_r agg_r @ W2[r]) / deg ), N padded 40->48
// 6 waves cover 2 row-halves x 3 col-tiles (48 cols).
// ---------------------------------------------------------------------------
__global__ __launch_bounds__(1024, 4)
void rgcn_layer2(const ushort* __restrict__ h1b,
                 const ushort* __restrict__ W2hi,
                 const int* __restrict__ ptr, const int* __restrict__ idx,
                 const int* __restrict__ etype,
                 float* __restrict__ out)
{
    __shared__ ushort aggHi[kNT][kLds];           // 66 KB
    __shared__ float logits[kNT][48];             // 6 KB
    const int tid  = threadIdx.x;
    const int base = blockIdx.x * kNT;

    phaseA_bf16(h1b, ptr, idx, etype, base, aggHi);
    __syncthreads();

    const int lane = tid & 63;
    const int wid  = tid >> 6;
    const int m    = lane & 15;
    const int q    = lane >> 4;

    if (wid < 6) {
        const int ni = wid >> 1;                  // col tile 0..2
        const int mi = wid & 1;                   // row half 0..1
        const bf16x8* Bh = (const bf16x8*)W2hi + (size_t)ni * 32 * 64 + lane;
        f32x4 acc = {0.f, 0.f, 0.f, 0.f};
        #pragma unroll 4
        for (int kt = 0; kt < 32; ++kt) {
            const bf16x8 ah = *(const bf16x8*)&aggHi[mi * 16 + m][kt * 32 + q * 8];
            const bf16x8 bh = Bh[(size_t)kt * 64];
            acc = __builtin_amdgcn_mfma_f32_16x16x32_bf16(ah, bh, acc, 0, 0, 0);
        }
        const int n = ni * 16 + m;                // logit column
        if (n < kOut) {
            #pragma unroll
            for (int i = 0; i < 4; ++i) {
                const int node = base + mi * 16 + q * 4 + i;
                if (node < kN) {
                    const float invdeg = 1.0f / (float)(ptr[node + 1] - ptr[node]);
                    logits[mi * 16 + q * 4 + i][n] = acc[i] * invdeg;
                }
            }
        }
    }
    __syncthreads();

    // log_softmax: wave w handles rows w*2, w*2+1
    #pragma unroll
    for (int i = 0; i < 2; ++i) {
        const int nrow = wid * 2 + i;
        const int node = base + nrow;
        if (node < kN) {
            const float v = (lane < kOut) ? logits[nrow][lane] : -INFINITY;
            float mx = v;
            #pragma unroll
            for (int off = 32; off > 0; off >>= 1)
                mx = fmaxf(mx, __shfl_xor(mx, off, 64));
            float s = (lane < kOut) ? __expf(v - mx) : 0.f;
            #pragma unroll
            for (int off = 32; off > 0; off >>= 1)
                s += __shfl_xor(s, off, 64);
            if (lane < kOut)
                out[(size_t)node * kOut + lane] = v - mx - __logf(s);
        }
    }
}

// ---------------------------------------------------------------------------
extern "C" void kernel_launch(void* const* d_in, const int* in_sizes, int n_in,
                              void* d_out, int out_size, void* d_ws, size_t ws_size,
                              hipStream_t stream)
{
    const float* x     = (const float*)d_in[0];
    const float* W1    = (const float*)d_in[1];
    const float* W2    = (const float*)d_in[2];
    const float* gamma = (const float*)d_in[3];
    const float* beta  = (const float*)d_in[4];
    const float* mean  = (const float*)d_in[5];
    const float* var   = (const float*)d_in[6];
    const int*   ptr   = (const int*)d_in[7];
    const int*   idx   = (const int*)d_in[8];
    const int*   et    = (const int*)d_in[9];
    float*       out   = (float*)d_out;

    // Workspace (~26 MB)
    char* ws = (char*)d_ws;
    ushort* h1b  = (ushort*)ws;                              // 12,800,000 B
    ushort* xb   = (ushort*)(ws + 12800000);                 // 12,800,000 B
    ushort* W1hi = (ushort*)(ws + 25600000);                 //    262,144 B
    ushort* W2hi = (ushort*)(ws + 25600000 + 262144);        //     98,304 B

    prep<<<dim3(3125 + 64 + 24), dim3(256), 0, stream>>>(x, xb, W1, W1hi, W2, W2hi);

    const int grid = (kN + kNT - 1) / kNT;                   // 1563
    rgcn_layer1<<<dim3(grid), dim3(1024), 0, stream>>>(xb, W1hi, gamma, beta, mean, var,
                                                       ptr, idx, et, h1b);
    rgcn_layer2<<<dim3(grid), dim3(1024), 0, stream>>>(h1b, W2hi, ptr, idx, et, out);
}

// Round 6
// 196.586 us; speedup vs baseline: 1.1021x; 1.0156x over previous
//
#include <hip/hip_runtime.h>
#include <math.h>

typedef __attribute__((ext_vector_type(8))) short bf16x8;
typedef __attribute__((ext_vector_type(4))) float f32x4;

constexpr int kN   = 50000;
constexpr int kIn  = 128;
constexpr int kHid = 128;
constexpr int kOut = 40;
constexpr int kNT  = 16;              // dst nodes per block (8 waves x 2)
constexpr int kLds = 1032;            // ushort row stride of aggHi
constexpr float kBnEps = 1e-5f;

// bf16 helpers
__device__ inline float bf2f(ushort s) { return __uint_as_float(((uint)s) << 16); }

// pure-C RNE fp32->bf16 (no inline asm; compiler handles MFMA->VALU hazards)
__device__ __forceinline__ ushort f2bf(float x) {
    uint u = __float_as_uint(x);
    u += 0x7FFFu + ((u >> 16) & 1u);
    return (ushort)(u >> 16);
}

// v_cvt_pk_bf16_f32: lo = bf16(a), hi = bf16(b), RNE. No builtin on gfx950.
// ONLY used where inputs come from compiler-generated VALU ops (proven paths).
__device__ __forceinline__ uint cvtpk(float a, float b) {
    uint r;
    asm("v_cvt_pk_bf16_f32 %0, %1, %2" : "=v"(r) : "v"(a), "v"(b));
    return r;
}

// ---------------------------------------------------------------------------
// prep: fused  (a) cast x fp32->bf16   [blocks 0..3124, 256 thr x 8 elems]
//              (b) pack W1 into MFMA B-fragment order [blocks 3125..3188]
//              (c) pack W2                            [blocks 3189..3212]
// Fragment f = nt*32 + kt; lane L holds B[n = nt*16 + (L&15)][k = kt*32 + (L>>4)*8 + j].
// ---------------------------------------------------------------------------
__device__ __forceinline__ void pack_unit(const float* __restrict__ W,
                                          ushort* __restrict__ dst,
                                          int N, int frag, int lane)
{
    const int kt = frag & 31;
    const int nt = frag >> 5;
    const int n  = nt * 16 + (lane & 15);
    const int q  = lane >> 4;
    float f[8];
    #pragma unroll
    for (int j = 0; j < 8; ++j) {
        const int k = kt * 32 + q * 8 + j;
        f[j] = (n < N) ? W[(size_t)k * N + n] : 0.f;
    }
    const size_t o = ((size_t)frag * 64 + lane) * 8;
    *(uint4*)&dst[o] = make_uint4(cvtpk(f[0], f[1]), cvtpk(f[2], f[3]),
                                  cvtpk(f[4], f[5]), cvtpk(f[6], f[7]));
}

__global__ __launch_bounds__(256)
void prep(const float* __restrict__ x,  ushort* __restrict__ xb,
          const float* __restrict__ W1, ushort* __restrict__ W1hi,
          const float* __restrict__ W2, ushort* __restrict__ W2hi)
{
    const int b   = blockIdx.x;
    const int tid = threadIdx.x;
    if (b < 3125) {
        const size_t i = ((size_t)b * 256 + tid) * 8;
        const float4 v0 = *(const float4*)&x[i];
        const float4 v1 = *(const float4*)&x[i + 4];
        *(uint4*)&xb[i] = make_uint4(cvtpk(v0.x, v0.y), cvtpk(v0.z, v0.w),
                                     cvtpk(v1.x, v1.y), cvtpk(v1.z, v1.w));
    } else if (b < 3125 + 64) {
        pack_unit(W1, W1hi, kHid, (b - 3125) * 4 + (tid >> 6), tid & 63);
    } else {
        const int frag = (b - 3189) * 4 + (tid >> 6);
        if (frag < 96) pack_unit(W2, W2hi, kOut, frag, tid & 63);
    }
}

// ---------------------------------------------------------------------------
// Phase A: per-wave one-hot-MFMA aggregation, REG-STAGED, ZERO inline asm.
//   Wave w owns nodes 2w,2w+1 (32 edges).  Neighbor rows staged into a
//   PRIVATE 4KB msgs region in two 64-feat halves.  LDS layout is swizzled:
//   physical_byte(e, logical_b) = e*128 + (logical_b ^ (((e>>3)&3)<<5)),
//   applied on the ds_write side; readB applies the same XOR -> the
//   transposed B-fragment reads are bank-conflict-free.
//   agg[c=(nloc,rel)][f] = sum_e S[c][e]*msgs[e][f]; S built in registers
//   from etype via __shfl (one-hot bf16), one MFMA per 16-feature tile.
// ---------------------------------------------------------------------------

// fast staging: round u, lane L covers edge e = u*8 + (L>>3), bytes (L&7)*16.
// Global read is LINEAR within the neighbor row; LDS write is swizzled.
__device__ __forceinline__ void stage_fast(const char* fb, int vi, char* msW,
                                           int hOff, int lane)
{
    const int b = (lane & 7) * 16;
    #pragma unroll
    for (int u = 0; u < 4; ++u) {
        const int e   = u * 8 + (lane >> 3);
        const int src = __shfl(vi, e, 64);
        const uint4 v = *(const uint4*)(fb + (((size_t)(uint)src) << 8) + hOff + b);
        *(uint4*)(msW + e * 128 + (b ^ (u << 5))) = v;   // u == (e>>3)&3
    }
}

// slow fallback (non-16-degree; never hit for this input: ptr = arange*16).
// Caps degree at 16/node.
__device__ __forceinline__ void stage_slow(const char* fb,
                                           const int* __restrict__ idx,
                                           int p0, int p1, int deg0, int deg1,
                                           char* msW, int hOff, int lane)
{
    const int l31 = lane & 31;
    if (lane < 32) {
        for (int e = 0; e < 32; ++e) {
            const bool eok = (e < 16) ? (e < deg0) : ((e - 16) < deg1);
            uint val = 0;
            if (eok) {
                const int g = (e < 16) ? (p0 + e) : (p1 + (e - 16));
                const int s = idx[g];
                val = *(const uint*)(fb + (((size_t)(uint)s) << 8) + hOff + l31 * 4);
            }
            *(uint*)(msW + e * 128 + ((l31 * 4) ^ (((e >> 3) & 3) << 5))) = val;
        }
    }
}

// B-fragment: lane (m,q) element j = msgs[e = q*8+j][f = ntL*16 + m]
// physical byte = e*128 + ((2m + ntL*32) ^ ((e>>3)<<5)) = e*128 + 2m + ((ntL^q)<<5)
__device__ __forceinline__ bf16x8 readB(const char* msW, int q, int m, int ntL)
{
    const char* ap = msW + q * 1024 + 2 * m + (((ntL ^ q) & 3) << 5);
    bf16x8 b;
    #pragma unroll
    for (int j = 0; j < 8; ++j) b[j] = *(const short*)(ap + j * 128);
    return b;
}

// D lane(m,q) reg i = D[c' = q*4+i][fl = m]; c' = nloc*8 + rel ->
// nloc = q>>1, rel = (q&1)*4 + i; aggHi k-index = rel*128 + (fbase + ntL*16 + m)
__device__ __forceinline__ void mfma_store(bf16x8 aS, bf16x8 bb, int fbase,
                                           int ntL, int w, int q, int m,
                                           ushort (*aggHi)[kLds])
{
    f32x4 z = {0.f, 0.f, 0.f, 0.f};
    const f32x4 d = __builtin_amdgcn_mfma_f32_16x16x32_bf16(aS, bb, z, 0, 0, 0);
    ushort* dst = &aggHi[2 * w + (q >> 1)][0];
    const int fcol = fbase + ntL * 16 + m;
    const int rb   = (q & 1) * 4;
    dst[(rb + 0) * 128 + fcol] = f2bf(d[0]);
    dst[(rb + 1) * 128 + fcol] = f2bf(d[1]);
    dst[(rb + 2) * 128 + fcol] = f2bf(d[2]);
    dst[(rb + 3) * 128 + fcol] = f2bf(d[3]);
}

__device__ __forceinline__ void phaseA_mfma(const ushort* __restrict__ feat,
                                            const int* __restrict__ ptr,
                                            const int* __restrict__ idx,
                                            const int* __restrict__ etype,
                                            int base, ushort (*aggHi)[kLds],
                                            char* msgs)
{
    const int lane = threadIdx.x & 63;
    const int w    = threadIdx.x >> 6;            // 8 waves
    const int m    = lane & 15;
    const int q    = lane >> 4;
    const char* fb = (const char*)feat;

    const int node0 = base + 2 * w;
    const int p0 = ptr[node0];
    const int p1 = ptr[node0 + 1];
    const int p2 = ptr[node0 + 2];
    const int deg0 = p1 - p0, deg1 = p2 - p1;
    const bool fast = (deg0 == 16) && (deg1 == 16);

    const int vi = idx  [p0 + (lane & 31)];       // 32 edges in lanes 0..31
    const int ve = etype[p0 + (lane & 31)];

    char* msW = msgs + w * 4096;

    // per-lane one-hot code for edge (lane&31): nloc*8 + etype; 0xFF = none
    int code;
    if (fast) {
        code = (((lane & 31) >> 4) << 3) | ve;
    } else {
        const int l31 = lane & 31;
        const bool eok = (l31 < 16) ? (l31 < deg0) : ((l31 - 16) < deg1);
        code = eok ? (((l31 >> 4) << 3) | ve) : 0xFF;
    }

    // one-hot A-fragment: A[c = m][e = q*8+j] = (code[e] == c) in bf16
    bf16x8 aS;
    #pragma unroll
    for (int j = 0; j < 8; ++j) {
        const int cj = __shfl(code, q * 8 + j, 64);
        aS[j] = (cj == m) ? (short)0x3F80 : (short)0;
    }

    // ---- half 0: stage, read B-frags
    if (fast) stage_fast(fb, vi, msW, 0, lane);
    else      stage_slow(fb, idx, p0, p1, deg0, deg1, msW, 0, lane);
    const bf16x8 b0 = readB(msW, q, m, 0);
    const bf16x8 b1 = readB(msW, q, m, 1);
    const bf16x8 b2 = readB(msW, q, m, 2);
    const bf16x8 b3 = readB(msW, q, m, 3);

    // ---- half 1 staging issues while half-0 MFMAs run (DS in-order keeps
    // the overwrite behind the b* reads; compiler tracks the aliasing deps)
    if (fast) stage_fast(fb, vi, msW, 128, lane);
    else      stage_slow(fb, idx, p0, p1, deg0, deg1, msW, 128, lane);

    mfma_store(aS, b0, 0, 0, w, q, m, aggHi);
    mfma_store(aS, b1, 0, 1, w, q, m, aggHi);
    mfma_store(aS, b2, 0, 2, w, q, m, aggHi);
    mfma_store(aS, b3, 0, 3, w, q, m, aggHi);

    // ---- half 1 B-frags + MFMAs
    const bf16x8 c0 = readB(msW, q, m, 0);
    const bf16x8 c1 = readB(msW, q, m, 1);
    const bf16x8 c2 = readB(msW, q, m, 2);
    const bf16x8 c3 = readB(msW, q, m, 3);
    mfma_store(aS, c0, 64, 0, w, q, m, aggHi);
    mfma_store(aS, c1, 64, 1, w, q, m, aggHi);
    mfma_store(aS, c2, 64, 2, w, q, m, aggHi);
    mfma_store(aS, c3, 64, 3, w, q, m, aggHi);
}

// ---------------------------------------------------------------------------
// Layer 1: h1 = bf16( relu(bn( (sum_r agg_r @ W1[r]) / deg )) )
// ---------------------------------------------------------------------------
__global__ __launch_bounds__(512, 4)
void rgcn_layer1(const ushort* __restrict__ xb,
                 const ushort* __restrict__ W1hi,
                 const float* __restrict__ gamma, const float* __restrict__ beta,
                 const float* __restrict__ mean,  const float* __restrict__ var,
                 const int* __restrict__ ptr, const int* __restrict__ idx,
                 const int* __restrict__ etype,
                 ushort* __restrict__ h1b)
{
    __shared__ ushort aggHi[kNT][kLds];              // 33,024 B
    __shared__ __align__(16) char msgs[8 * 4096];    // 32,768 B
    const int tid  = threadIdx.x;
    const int base = blockIdx.x * kNT;

    phaseA_mfma(xb, ptr, idx, etype, base, aggHi, msgs);
    __syncthreads();

    const int lane = tid & 63;
    const int wid  = tid >> 6;                    // n-tile owned by this wave
    const int m    = lane & 15;
    const int q    = lane >> 4;

    const bf16x8* Bh = (const bf16x8*)W1hi + (size_t)wid * 32 * 64 + lane;
    f32x4 acc = {0.f, 0.f, 0.f, 0.f};

    #pragma unroll 4
    for (int kt = 0; kt < 32; ++kt) {
        const bf16x8 ah = *(const bf16x8*)&aggHi[m][kt * 32 + q * 8];
        const bf16x8 bh = Bh[(size_t)kt * 64];
        acc = __builtin_amdgcn_mfma_f32_16x16x32_bf16(ah, bh, acc, 0, 0, 0);
    }

    // Epilogue: deg norm + BN + ReLU, write bf16 h1 (packed conversions)
    const int c = wid * 16 + m;
    const float g  = gamma[c] * rsqrtf(var[c] + kBnEps);
    const float mu = mean[c];
    const float bt = beta[c];
    float v[4];
    #pragma unroll
    for (int i = 0; i < 4; ++i) {
        const int node = base + q * 4 + i;
        const float invdeg = 1.0f / (float)(ptr[node + 1] - ptr[node]);
        v[i] = fmaxf((acc[i] * invdeg - mu) * g + bt, 0.f);
    }
    const uint p01 = cvtpk(v[0], v[1]);
    const uint p23 = cvtpk(v[2], v[3]);
    const int n0 = base + q * 4;
    h1b[(size_t)(n0 + 0) * kHid + c] = (ushort)(p01 & 0xFFFFu);
    h1b[(size_t)(n0 + 1) * kHid + c] = (ushort)(p01 >> 16);
    h1b[(size_t)(n0 + 2) * kHid + c] = (ushort)(p23 & 0xFFFFu);
    h1b[(size_t)(n0 + 3) * kHid + c] = (ushort)(p23 >> 16);
}

// ---------------------------------------------------------------------------
// Layer 2: out = log_softmax( (sum_r agg_r @ W2[r]) / deg ), N padded 40->48
// ---------------------------------------------------------------------------
__global__ __launch_bounds__(512, 4)
void rgcn_layer2(const ushort* __restrict__ h1b,
                 const ushort* __restrict__ W2hi,
                 const int* __restrict__ ptr, const int* __restrict__ idx,
                 const int* __restrict__ etype,
                 float* __restrict__ out)
{
    __shared__ ushort aggHi[kNT][kLds];              // 33,024 B
    __shared__ __align__(16) char msgs[8 * 4096];    // 32,768 B
    __shared__ float logits[kNT][48];                //  3,072 B
    const int tid  = threadIdx.x;
    const int base = blockIdx.x * kNT;

    phaseA_mfma(h1b, ptr, idx, etype, base, aggHi, msgs);
    __syncthreads();

    const int lane = tid & 63;
    const int wid  = tid >> 6;
    const int m    = lane & 15;
    const int q    = lane >> 4;

    if (wid < 3) {                                // n-tiles 0..2 cover 48 cols
        const bf16x8* Bh = (const bf16x8*)W2hi + (size_t)wid * 32 * 64 + lane;
        f32x4 acc = {0.f, 0.f, 0.f, 0.f};
        #pragma unroll 4
        for (int kt = 0; kt < 32; ++kt) {
            const bf16x8 ah = *(const bf16x8*)&aggHi[m][kt * 32 + q * 8];
            const bf16x8 bh = Bh[(size_t)kt * 64];
            acc = __builtin_amdgcn_mfma_f32_16x16x32_bf16(ah, bh, acc, 0, 0, 0);
        }
        const int n = wid * 16 + m;               // logit column
        if (n < kOut) {
            #pragma unroll
            for (int i = 0; i < 4; ++i) {
                const int node = base + q * 4 + i;
                const float invdeg = 1.0f / (float)(ptr[node + 1] - ptr[node]);
                logits[q * 4 + i][n] = acc[i] * invdeg;
            }
        }
    }
    __syncthreads();

    // log_softmax: wave w handles nodes w*2, w*2+1
    #pragma unroll
    for (int i = 0; i < 2; ++i) {
        const int nrow = wid * 2 + i;
        const int node = base + nrow;
        const float v = (lane < kOut) ? logits[nrow][lane] : -INFINITY;
        float mx = v;
        #pragma unroll
        for (int off = 32; off > 0; off >>= 1)
            mx = fmaxf(mx, __shfl_xor(mx, off, 64));
        float s = (lane < kOut) ? __expf(v - mx) : 0.f;
        #pragma unroll
        for (int off = 32; off > 0; off >>= 1)
            s += __shfl_xor(s, off, 64);
        if (lane < kOut)
            out[(size_t)node * kOut + lane] = v - mx - __logf(s);
    }
}

// ---------------------------------------------------------------------------
extern "C" void kernel_launch(void* const* d_in, const int* in_sizes, int n_in,
                              void* d_out, int out_size, void* d_ws, size_t ws_size,
                              hipStream_t stream)
{
    const float* x     = (const float*)d_in[0];
    const float* W1    = (const float*)d_in[1];
    const float* W2    = (const float*)d_in[2];
    const float* gamma = (const float*)d_in[3];
    const float* beta  = (const float*)d_in[4];
    const float* mean  = (const float*)d_in[5];
    const float* var   = (const float*)d_in[6];
    const int*   ptr   = (const int*)d_in[7];
    const int*   idx   = (const int*)d_in[8];
    const int*   et    = (const int*)d_in[9];
    float*       out   = (float*)d_out;

    // Workspace (~26 MB)
    char* ws = (char*)d_ws;
    ushort* h1b  = (ushort*)ws;                              // 12,800,000 B
    ushort* xb   = (ushort*)(ws + 12800000);                 // 12,800,000 B
    ushort* W1hi = (ushort*)(ws + 25600000);                 //    262,144 B
    ushort* W2hi = (ushort*)(ws + 25600000 + 262144);        //     98,304 B

    prep<<<dim3(3125 + 64 + 24), dim3(256), 0, stream>>>(x, xb, W1, W1hi, W2, W2hi);

    dim3 grid(kN / kNT), block(512);
    rgcn_layer1<<<grid, block, 0, stream>>>(xb, W1hi, gamma, beta, mean, var,
                                            ptr, idx, et, h1b);
    rgcn_layer2<<<grid, block, 0, stream>>>(h1b, W2hi, ptr, idx, et, out);
}

// Round 7
// 184.947 us; speedup vs baseline: 1.1714x; 1.0629x over previous
//
#include <hip/hip_runtime.h>
#include <math.h>

typedef __attribute__((ext_vector_type(8))) short bf16x8;
typedef __attribute__((ext_vector_type(4))) float f32x4;

constexpr int kN   = 50000;
constexpr int kIn  = 128;
constexpr int kHid = 128;
constexpr int kOut = 40;
constexpr int kNT  = 16;              // dst nodes per block (8 waves x 2)
constexpr int kLds = 1032;            // ushort row stride of aggHi
constexpr float kBnEps = 1e-5f;

// Workspace layout (bytes):
//   [0, 262144)            W1hi   (256 frags x 64 x 8 ushort)
//   [262144, 360448)       W2hi   ( 96 frags)  -- fallback path
//   [360448, 491520)       W2z    (128 frags)  -- z path
//   [524288, +12.8MB)      xb
//   [13324288, ...)        h1b (12.8MB, fallback)  OR  z (51.2MB, useZ)
constexpr size_t kOffW2hi = 262144;
constexpr size_t kOffW2z  = 360448;
constexpr size_t kOffXb   = 524288;
constexpr size_t kOffBig  = 13324288;
constexpr size_t kZBytes  = (size_t)kN * 512 * 2;        // 51,200,000

// bf16 helpers
__device__ inline float bf2f(ushort s) { return __uint_as_float(((uint)s) << 16); }

// pure-C RNE fp32->bf16 (no inline asm; compiler handles MFMA->VALU hazards)
__device__ __forceinline__ ushort f2bf(float x) {
    uint u = __float_as_uint(x);
    u += 0x7FFFu + ((u >> 16) & 1u);
    return (ushort)(u >> 16);
}

// v_cvt_pk_bf16_f32: lo = bf16(a), hi = bf16(b), RNE. No builtin on gfx950.
// ONLY used where inputs come from compiler-generated VALU ops (proven paths).
__device__ __forceinline__ uint cvtpk(float a, float b) {
    uint r;
    asm("v_cvt_pk_bf16_f32 %0, %1, %2" : "=v"(r) : "v"(a), "v"(b));
    return r;
}

#define RD(V, J) __builtin_amdgcn_readlane((V), (J))

// ---------------------------------------------------------------------------
// prep: fused  (a) cast x fp32->bf16            [blocks 0..3124]
//              (b) pack W1 -> B-frag order      [blocks 3125..3188]
//              (c) pack W2 -> W2hi (fallback)   [blocks 3189..3212]
//              (d) pack W2 -> W2z (512-col, z)  [blocks 3213..3244]
// Fragment f = nt*KT + kt; lane L holds B[c = nt*16 + (L&15)][k = kt*32 + (L>>4)*8 + j].
// ---------------------------------------------------------------------------
__device__ __forceinline__ void pack_unit(const float* __restrict__ W,
                                          ushort* __restrict__ dst,
                                          int N, int frag, int lane)
{
    const int kt = frag & 31;
    const int nt = frag >> 5;
    const int n  = nt * 16 + (lane & 15);
    const int q  = lane >> 4;
    float f[8];
    #pragma unroll
    for (int j = 0; j < 8; ++j) {
        const int k = kt * 32 + q * 8 + j;
        f[j] = (n < N) ? W[(size_t)k * N + n] : 0.f;
    }
    const size_t o = ((size_t)frag * 64 + lane) * 8;
    *(uint4*)&dst[o] = make_uint4(cvtpk(f[0], f[1]), cvtpk(f[2], f[3]),
                                  cvtpk(f[4], f[5]), cvtpk(f[6], f[7]));
}

__global__ __launch_bounds__(256)
void prep(const float* __restrict__ x,  ushort* __restrict__ xb,
          const float* __restrict__ W1, ushort* __restrict__ W1hi,
          const float* __restrict__ W2, ushort* __restrict__ W2hi,
          ushort* __restrict__ W2z, int useZ)
{
    const int b   = blockIdx.x;
    const int tid = threadIdx.x;
    if (b < 3125) {
        const size_t i = ((size_t)b * 256 + tid) * 8;
        const float4 v0 = *(const float4*)&x[i];
        const float4 v1 = *(const float4*)&x[i + 4];
        *(uint4*)&xb[i] = make_uint4(cvtpk(v0.x, v0.y), cvtpk(v0.z, v0.w),
                                     cvtpk(v1.x, v1.y), cvtpk(v1.z, v1.w));
    } else if (b < 3125 + 64) {
        pack_unit(W1, W1hi, kHid, (b - 3125) * 4 + (tid >> 6), tid & 63);
    } else if (b < 3213) {
        const int frag = (b - 3189) * 4 + (tid >> 6);
        if (frag < 96) pack_unit(W2, W2hi, kOut, frag, tid & 63);
    } else if (useZ) {
        // W2z: 512 cols c = r*64 + o (o<40 real, else 0); K = 128; KT = 4.
        const int frag = (b - 3213) * 4 + (tid >> 6);     // 0..127
        const int kt   = frag & 3;
        const int nt   = frag >> 2;                       // 0..31
        const int lane = tid & 63;
        const int c    = nt * 16 + (lane & 15);
        const int r    = c >> 6;
        const int o    = c & 63;
        const int q    = lane >> 4;
        float f[8];
        #pragma unroll
        for (int j = 0; j < 8; ++j) {
            const int k = kt * 32 + q * 8 + j;
            f[j] = (o < kOut) ? W2[((size_t)r * kHid + k) * kOut + o] : 0.f;
        }
        const size_t of = ((size_t)frag * 64 + lane) * 8;
        *(uint4*)&W2z[of] = make_uint4(cvtpk(f[0], f[1]), cvtpk(f[2], f[3]),
                                       cvtpk(f[4], f[5]), cvtpk(f[6], f[7]));
    }
}

// ---------------------------------------------------------------------------
// Phase A (R6-proven): per-wave one-hot-MFMA aggregation, reg-staged, no asm.
// ---------------------------------------------------------------------------
__device__ __forceinline__ void stage_fast(const char* fb, int vi, char* msW,
                                           int hOff, int lane)
{
    const int b = (lane & 7) * 16;
    #pragma unroll
    for (int u = 0; u < 4; ++u) {
        const int e   = u * 8 + (lane >> 3);
        const int src = __shfl(vi, e, 64);
        const uint4 v = *(const uint4*)(fb + (((size_t)(uint)src) << 8) + hOff + b);
        *(uint4*)(msW + e * 128 + (b ^ (u << 5))) = v;   // u == (e>>3)&3
    }
}

__device__ __forceinline__ void stage_slow(const char* fb,
                                           const int* __restrict__ idx,
                                           int p0, int p1, int deg0, int deg1,
                                           char* msW, int hOff, int lane)
{
    const int l31 = lane & 31;
    if (lane < 32) {
        for (int e = 0; e < 32; ++e) {
            const bool eok = (e < 16) ? (e < deg0) : ((e - 16) < deg1);
            uint val = 0;
            if (eok) {
                const int g = (e < 16) ? (p0 + e) : (p1 + (e - 16));
                const int s = idx[g];
                val = *(const uint*)(fb + (((size_t)(uint)s) << 8) + hOff + l31 * 4);
            }
            *(uint*)(msW + e * 128 + ((l31 * 4) ^ (((e >> 3) & 3) << 5))) = val;
        }
    }
}

__device__ __forceinline__ bf16x8 readB(const char* msW, int q, int m, int ntL)
{
    const char* ap = msW + q * 1024 + 2 * m + (((ntL ^ q) & 3) << 5);
    bf16x8 b;
    #pragma unroll
    for (int j = 0; j < 8; ++j) b[j] = *(const short*)(ap + j * 128);
    return b;
}

__device__ __forceinline__ void mfma_store(bf16x8 aS, bf16x8 bb, int fbase,
                                           int ntL, int w, int q, int m,
                                           ushort (*aggHi)[kLds])
{
    f32x4 z = {0.f, 0.f, 0.f, 0.f};
    const f32x4 d = __builtin_amdgcn_mfma_f32_16x16x32_bf16(aS, bb, z, 0, 0, 0);
    ushort* dst = &aggHi[2 * w + (q >> 1)][0];
    const int fcol = fbase + ntL * 16 + m;
    const int rb   = (q & 1) * 4;
    dst[(rb + 0) * 128 + fcol] = f2bf(d[0]);
    dst[(rb + 1) * 128 + fcol] = f2bf(d[1]);
    dst[(rb + 2) * 128 + fcol] = f2bf(d[2]);
    dst[(rb + 3) * 128 + fcol] = f2bf(d[3]);
}

__device__ __forceinline__ void phaseA_mfma(const ushort* __restrict__ feat,
                                            const int* __restrict__ ptr,
                                            const int* __restrict__ idx,
                                            const int* __restrict__ etype,
                                            int base, ushort (*aggHi)[kLds],
                                            char* msgs)
{
    const int lane = threadIdx.x & 63;
    const int w    = threadIdx.x >> 6;            // 8 waves
    const int m    = lane & 15;
    const int q    = lane >> 4;
    const char* fb = (const char*)feat;

    const int node0 = base + 2 * w;
    const int p0 = ptr[node0];
    const int p1 = ptr[node0 + 1];
    const int p2 = ptr[node0 + 2];
    const int deg0 = p1 - p0, deg1 = p2 - p1;
    const bool fast = (deg0 == 16) && (deg1 == 16);

    const int vi = idx  [p0 + (lane & 31)];       // 32 edges in lanes 0..31
    const int ve = etype[p0 + (lane & 31)];

    char* msW = msgs + w * 4096;

    int code;
    if (fast) {
        code = (((lane & 31) >> 4) << 3) | ve;
    } else {
        const int l31 = lane & 31;
        const bool eok = (l31 < 16) ? (l31 < deg0) : ((l31 - 16) < deg1);
        code = eok ? (((l31 >> 4) << 3) | ve) : 0xFF;
    }

    bf16x8 aS;
    #pragma unroll
    for (int j = 0; j < 8; ++j) {
        const int cj = __shfl(code, q * 8 + j, 64);
        aS[j] = (cj == m) ? (short)0x3F80 : (short)0;
    }

    if (fast) stage_fast(fb, vi, msW, 0, lane);
    else      stage_slow(fb, idx, p0, p1, deg0, deg1, msW, 0, lane);
    const bf16x8 b0 = readB(msW, q, m, 0);
    const bf16x8 b1 = readB(msW, q, m, 1);
    const bf16x8 b2 = readB(msW, q, m, 2);
    const bf16x8 b3 = readB(msW, q, m, 3);

    if (fast) stage_fast(fb, vi, msW, 128, lane);
    else      stage_slow(fb, idx, p0, p1, deg0, deg1, msW, 128, lane);

    mfma_store(aS, b0, 0, 0, w, q, m, aggHi);
    mfma_store(aS, b1, 0, 1, w, q, m, aggHi);
    mfma_store(aS, b2, 0, 2, w, q, m, aggHi);
    mfma_store(aS, b3, 0, 3, w, q, m, aggHi);

    const bf16x8 c0 = readB(msW, q, m, 0);
    const bf16x8 c1 = readB(msW, q, m, 1);
    const bf16x8 c2 = readB(msW, q, m, 2);
    const bf16x8 c3 = readB(msW, q, m, 3);
    mfma_store(aS, c0, 64, 0, w, q, m, aggHi);
    mfma_store(aS, c1, 64, 1, w, q, m, aggHi);
    mfma_store(aS, c2, 64, 2, w, q, m, aggHi);
    mfma_store(aS, c3, 64, 3, w, q, m, aggHi);
}

// ---------------------------------------------------------------------------
// Layer 1: h1 = bf16( relu(bn( (sum_r agg_r @ W1[r]) / deg )) )
// useZ: additionally z[node][c=r*64+o] = h1 @ W2z (fused mini-GEMM via LDS),
//       h1b never materialized.  !useZ: write h1b (R6-identical).
// ---------------------------------------------------------------------------
__global__ __launch_bounds__(512, 4)
void rgcn_layer1(const ushort* __restrict__ xb,
                 const ushort* __restrict__ W1hi,
                 const ushort* __restrict__ W2z,
                 const float* __restrict__ gamma, const float* __restrict__ beta,
                 const float* __restrict__ mean,  const float* __restrict__ var,
                 const int* __restrict__ ptr, const int* __restrict__ idx,
                 const int* __restrict__ etype,
                 ushort* __restrict__ big, int useZ)
{
    __shared__ ushort aggHi[kNT][kLds];              // 33,024 B
    __shared__ __align__(16) char msgs[8 * 4096];    // 32,768 B
    const int tid  = threadIdx.x;
    const int base = blockIdx.x * kNT;

    phaseA_mfma(xb, ptr, idx, etype, base, aggHi, msgs);
    __syncthreads();

    const int lane = tid & 63;
    const int wid  = tid >> 6;                    // n-tile owned by this wave
    const int m    = lane & 15;
    const int q    = lane >> 4;

    const bf16x8* Bh = (const bf16x8*)W1hi + (size_t)wid * 32 * 64 + lane;
    f32x4 acc = {0.f, 0.f, 0.f, 0.f};

    #pragma unroll 4
    for (int kt = 0; kt < 32; ++kt) {
        const bf16x8 ah = *(const bf16x8*)&aggHi[m][kt * 32 + q * 8];
        const bf16x8 bh = Bh[(size_t)kt * 64];
        acc = __builtin_amdgcn_mfma_f32_16x16x32_bf16(ah, bh, acc, 0, 0, 0);
    }

    // Epilogue: deg norm + BN + ReLU -> bf16 h1
    const int c = wid * 16 + m;
    const float g  = gamma[c] * rsqrtf(var[c] + kBnEps);
    const float mu = mean[c];
    const float bt = beta[c];
    float v[4];
    #pragma unroll
    for (int i = 0; i < 4; ++i) {
        const int node = base + q * 4 + i;
        const float invdeg = 1.0f / (float)(ptr[node + 1] - ptr[node]);
        v[i] = fmaxf((acc[i] * invdeg - mu) * g + bt, 0.f);
    }
    const uint p01 = cvtpk(v[0], v[1]);
    const uint p23 = cvtpk(v[2], v[3]);

    if (useZ) {
        // h1 tile -> LDS (msgs high region), rows = local node, 136-pad
        ushort (*h1lds)[136] = (ushort (*)[136])(msgs + 16384);
        h1lds[q * 4 + 0][c] = (ushort)(p01 & 0xFFFFu);
        h1lds[q * 4 + 1][c] = (ushort)(p01 >> 16);
        h1lds[q * 4 + 2][c] = (ushort)(p23 & 0xFFFFu);
        h1lds[q * 4 + 3][c] = (ushort)(p23 >> 16);
        __syncthreads();

        // mini-GEMM: z_tile[16][512] = h1_tile[16][128] @ W2z; K=128 (4 kt)
        ushort (*zlds)[512] = (ushort (*)[512])msgs;
        const bf16x8* B2 = (const bf16x8*)W2z;
        #pragma unroll
        for (int t = 0; t < 4; ++t) {
            const int nt = wid * 4 + t;           // 0..31
            f32x4 a2 = {0.f, 0.f, 0.f, 0.f};
            #pragma unroll
            for (int kt2 = 0; kt2 < 4; ++kt2) {
                const bf16x8 ah2 = *(const bf16x8*)&h1lds[m][kt2 * 32 + q * 8];
                const bf16x8 bh2 = B2[(size_t)(nt * 4 + kt2) * 64 + lane];
                a2 = __builtin_amdgcn_mfma_f32_16x16x32_bf16(ah2, bh2, a2, 0, 0, 0);
            }
            zlds[q * 4 + 0][nt * 16 + m] = f2bf(a2[0]);
            zlds[q * 4 + 1][nt * 16 + m] = f2bf(a2[1]);
            zlds[q * 4 + 2][nt * 16 + m] = f2bf(a2[2]);
            zlds[q * 4 + 3][nt * 16 + m] = f2bf(a2[3]);
        }
        __syncthreads();

        // coalesced copyout: 512 thr x 32B = 16KB tile
        const int row = tid >> 5;
        const int cs  = (tid & 31) * 16;          // ushort offset in row
        ushort* zp = big + ((size_t)(base + row)) * 512 + cs;
        *(uint4*)zp       = *(const uint4*)&zlds[row][cs];
        *(uint4*)(zp + 8) = *(const uint4*)&zlds[row][cs + 8];
    } else {
        const int n0 = base + q * 4;
        big[(size_t)(n0 + 0) * kHid + c] = (ushort)(p01 & 0xFFFFu);
        big[(size_t)(n0 + 1) * kHid + c] = (ushort)(p01 >> 16);
        big[(size_t)(n0 + 2) * kHid + c] = (ushort)(p23 & 0xFFFFu);
        big[(size_t)(n0 + 3) * kHid + c] = (ushort)(p23 >> 16);
    }
}

// ---------------------------------------------------------------------------
// Layer 2 (fallback, R6-verbatim): agg(h1b) @ W2hi -> log_softmax
// ---------------------------------------------------------------------------
__global__ __launch_bounds__(512, 4)
void rgcn_layer2(const ushort* __restrict__ h1b,
                 const ushort* __restrict__ W2hi,
                 const int* __restrict__ ptr, const int* __restrict__ idx,
                 const int* __restrict__ etype,
                 float* __restrict__ out)
{
    __shared__ ushort aggHi[kNT][kLds];
    __shared__ __align__(16) char msgs[8 * 4096];
    __shared__ float logits[kNT][48];
    const int tid  = threadIdx.x;
    const int base = blockIdx.x * kNT;

    phaseA_mfma(h1b, ptr, idx, etype, base, aggHi, msgs);
    __syncthreads();

    const int lane = tid & 63;
    const int wid  = tid >> 6;
    const int m    = lane & 15;
    const int q    = lane >> 4;

    if (wid < 3) {
        const bf16x8* Bh = (const bf16x8*)W2hi + (size_t)wid * 32 * 64 + lane;
        f32x4 acc = {0.f, 0.f, 0.f, 0.f};
        #pragma unroll 4
        for (int kt = 0; kt < 32; ++kt) {
            const bf16x8 ah = *(const bf16x8*)&aggHi[m][kt * 32 + q * 8];
            const bf16x8 bh = Bh[(size_t)kt * 64];
            acc = __builtin_amdgcn_mfma_f32_16x16x32_bf16(ah, bh, acc, 0, 0, 0);
        }
        const int n = wid * 16 + m;
        if (n < kOut) {
            #pragma unroll
            for (int i = 0; i < 4; ++i) {
                const int node = base + q * 4 + i;
                const float invdeg = 1.0f / (float)(ptr[node + 1] - ptr[node]);
                logits[q * 4 + i][n] = acc[i] * invdeg;
            }
        }
    }
    __syncthreads();

    #pragma unroll
    for (int i = 0; i < 2; ++i) {
        const int nrow = wid * 2 + i;
        const int node = base + nrow;
        const float v = (lane < kOut) ? logits[nrow][lane] : -INFINITY;
        float mx = v;
        #pragma unroll
        for (int off = 32; off > 0; off >>= 1)
            mx = fmaxf(mx, __shfl_xor(mx, off, 64));
        float s = (lane < kOut) ? __expf(v - mx) : 0.f;
        #pragma unroll
        for (int off = 32; off > 0; off >>= 1)
            s += __shfl_xor(s, off, 64);
        if (lane < kOut)
            out[(size_t)node * kOut + lane] = v - mx - __logf(s);
    }
}

// ---------------------------------------------------------------------------
// Layer 2z: out[i] = log_softmax( (sum_e z[idx[e]][et[e]*64 + :]) / deg ).
// Pure gather-sum-softmax: 128B/edge, no LDS, no barriers, no MFMA.
// Wave handles 4 nodes; lane = output column (lane<40 valid).
// ---------------------------------------------------------------------------
__global__ __launch_bounds__(256)
void rgcn_layer2z(const ushort* __restrict__ z,
                  const int* __restrict__ ptr, const int* __restrict__ idx,
                  const int* __restrict__ etype,
                  float* __restrict__ out)
{
    const int lane = threadIdx.x & 63;
    const int wv   = threadIdx.x >> 6;            // 4 waves
    const int n0   = blockIdx.x * 16 + wv * 4;

    const int p0 = ptr[n0];
    const int d0 = ptr[n0 + 1] - p0;
    const int d1 = ptr[n0 + 2] - ptr[n0 + 1];
    const int d2 = ptr[n0 + 3] - ptr[n0 + 2];
    const int d3 = ptr[n0 + 4] - ptr[n0 + 3];
    const bool fast = (d0 == 16) & (d1 == 16) & (d2 == 16) & (d3 == 16);

    int vi = 0, ve = 0;
    if (fast) { vi = idx[p0 + lane]; ve = etype[p0 + lane]; }

    #pragma unroll
    for (int t = 0; t < 4; ++t) {
        const int node = n0 + t;
        float acc = 0.f;
        float invdeg;
        if (fast) {
            invdeg = 0.0625f;
            #pragma unroll
            for (int j = 0; j < 16; ++j) {
                const int e = t * 16 + j;
                const int s = RD(vi, e);
                const int r = RD(ve, e);
                acc += bf2f(z[(size_t)(uint)s * 512 + r * 64 + lane]);
            }
        } else {
            const int pa = ptr[node], pb = ptr[node + 1];
            invdeg = 1.0f / (float)(pb - pa);
            for (int e = pa; e < pb; ++e) {
                const int s = __builtin_amdgcn_readfirstlane(idx[e]);
                const int r = __builtin_amdgcn_readfirstlane(etype[e]);
                acc += bf2f(z[(size_t)(uint)s * 512 + r * 64 + lane]);
            }
        }
        const float v = (lane < kOut) ? acc * invdeg : -INFINITY;
        float mx = v;
        #pragma unroll
        for (int off = 32; off > 0; off >>= 1)
            mx = fmaxf(mx, __shfl_xor(mx, off, 64));
        float s2 = (lane < kOut) ? __expf(v - mx) : 0.f;
        #pragma unroll
        for (int off = 32; off > 0; off >>= 1)
            s2 += __shfl_xor(s2, off, 64);
        if (lane < kOut)
            out[(size_t)node * kOut + lane] = v - mx - __logf(s2);
    }
}

// ---------------------------------------------------------------------------
extern "C" void kernel_launch(void* const* d_in, const int* in_sizes, int n_in,
                              void* d_out, int out_size, void* d_ws, size_t ws_size,
                              hipStream_t stream)
{
    const float* x     = (const float*)d_in[0];
    const float* W1    = (const float*)d_in[1];
    const float* W2    = (const float*)d_in[2];
    const float* gamma = (const float*)d_in[3];
    const float* beta  = (const float*)d_in[4];
    const float* mean  = (const float*)d_in[5];
    const float* var   = (const float*)d_in[6];
    const int*   ptr   = (const int*)d_in[7];
    const int*   idx   = (const int*)d_in[8];
    const int*   et    = (const int*)d_in[9];
    float*       out   = (float*)d_out;

    char* ws = (char*)d_ws;
    ushort* W1hi = (ushort*)ws;
    ushort* W2hi = (ushort*)(ws + kOffW2hi);
    ushort* W2z  = (ushort*)(ws + kOffW2z);
    ushort* xb   = (ushort*)(ws + kOffXb);
    ushort* big  = (ushort*)(ws + kOffBig);      // h1b (fallback) or z (useZ)

    const int useZ = (ws_size >= kOffBig + kZBytes) ? 1 : 0;

    prep<<<dim3(3245), dim3(256), 0, stream>>>(x, xb, W1, W1hi, W2, W2hi,
                                               W2z, useZ);

    dim3 grid(kN / kNT), block(512);
    rgcn_layer1<<<grid, block, 0, stream>>>(xb, W1hi, W2z, gamma, beta, mean,
                                            var, ptr, idx, et, big, useZ);
    if (useZ) {
        rgcn_layer2z<<<dim3(kN / 16), dim3(256), 0, stream>>>(big, ptr, idx,
                                                              et, out);
    } else {
        rgcn_layer2<<<grid, block, 0, stream>>>(big, W2hi, ptr, idx, et, out);
    }
}